// Round 7
// baseline (322.970 us; speedup 1.0000x reference)
//
#include <hip/hip_runtime.h>
#include <hip/hip_bf16.h>
#include <math.h>

#define NNODES 4096
#define NHEADS 4
#define MAXDEG 128

typedef __attribute__((ext_vector_type(8))) short  bf16x8;
typedef __attribute__((ext_vector_type(4))) float  f32x4;
typedef __attribute__((ext_vector_type(4))) unsigned short us4;

__device__ __forceinline__ unsigned short f2bf(float v) {
    unsigned int x = __float_as_uint(v);
    unsigned int r = (x + 0x7fffu + ((x >> 16) & 1u)) >> 16;   // RNE
    return (unsigned short)r;
}

__device__ __forceinline__ void gload_lds16(const unsigned short* g, unsigned short* l) {
    __builtin_amdgcn_global_load_lds(
        (const __attribute__((address_space(1))) unsigned int*)(g),
        (__attribute__((address_space(3))) unsigned int*)(l), 16, 0, 0);
}

// ---------------- CSR build with bitmap dedupe ----------------
__global__ __launch_bounds__(256) void build_csr(
    const int* __restrict__ er, const int* __restrict__ ec,
    unsigned int* __restrict__ bitmap, int* __restrict__ cnt,
    int* __restrict__ cols, int E)
{
    int e = blockIdx.x * 256 + threadIdx.x;
    if (e >= E) return;
    int r = er[e], c = ec[e];
    unsigned int idx = ((unsigned int)r << 12) | (unsigned int)c;
    unsigned int bit = 1u << (idx & 31);
    unsigned int old = atomicOr(&bitmap[idx >> 5], bit);
    if (!(old & bit)) {
        int slot = atomicAdd(&cnt[r], 1);
        if (slot < MAXDEG) cols[r * MAXDEG + slot] = c;
    }
}

// ---------------- fp32 -> bf16 elementwise (vectorized) ----------------
__global__ __launch_bounds__(256) void cvt_bf16(
    const float* __restrict__ in, unsigned short* __restrict__ out, int n4)
{
    int i = blockIdx.x * 256 + threadIdx.x;
    if (i >= n4) return;
    float4 v = *(const float4*)(in + (size_t)i * 4);
    us4 o; o.x = f2bf(v.x); o.y = f2bf(v.y); o.z = f2bf(v.z); o.w = f2bf(v.w);
    *(us4*)(out + (size_t)i * 4) = o;
}

// ---------------- W[h][k][j] fp32 -> Wt[h*256+j][K] bf16 (tiled transpose) ----------------
__global__ __launch_bounds__(256) void transpose_w(
    const float* __restrict__ W, unsigned short* __restrict__ Wt, int K)
{
    __shared__ float tile[32][33];
    int k0 = blockIdx.x * 32;
    int j0 = blockIdx.y * 32;
    int h  = blockIdx.z;
    int tj = threadIdx.x & 31;
    int tk = threadIdx.x >> 5;
#pragma unroll
    for (int it = 0; it < 4; ++it) {
        int kl = tk + it * 8;
        tile[kl][tj] = W[(size_t)h * K * 256 + (size_t)(k0 + kl) * 256 + j0 + tj];
    }
    __syncthreads();
#pragma unroll
    for (int it = 0; it < 4; ++it) {
        int jl = tk + it * 8;
        Wt[(size_t)(h * 256 + j0 + jl) * K + k0 + tj] = f2bf(tile[tj][jl]);
    }
}

// ---------------- bf16 MFMA GEMM, 64x64 tile, BK=64, single-buffer (232us cfg) ----
// Main blocks (bn<16): HEAD-MAJOR bf16 h store + fused wh1/wh2 ([node][4]) + colsum.
// Proj blocks (bn>=16, HASPROJ only): fp32 + bias into Cproj (stride 256).
template <int HASPROJ>
__global__ __launch_bounds__(256) void gemm_mfma(
    const unsigned short* __restrict__ A, const unsigned short* __restrict__ Bt,
    const unsigned short* __restrict__ pBt, const float* __restrict__ pb,
    float* __restrict__ Cproj, unsigned short* __restrict__ Cbf,
    const float* __restrict__ av, float* __restrict__ wh1, float* __restrict__ wh2,
    float* __restrict__ colsum, int K)
{
    __shared__ unsigned short As[64 * 64];   // 64 rows x 128B
    __shared__ unsigned short Bs[64 * 64];
    int tid = threadIdx.x;
    int lane = tid & 63;
    int wave = tid >> 6;
    int wr = wave >> 1, wc = wave & 1;
    int bn = blockIdx.x, bm = blockIdx.y;
    int tileM = bm * 64;
    bool isProj = HASPROJ && (bn >= 16);
    const unsigned short* B = isProj ? pBt + (size_t)(bn - 16) * 64 * K
                                     : Bt + (size_t)bn * 64 * K;

    f32x4 acc[2][2];
#pragma unroll
    for (int m = 0; m < 2; ++m)
#pragma unroll
        for (int n = 0; n < 2; ++n) acc[m][n] = (f32x4){0.f, 0.f, 0.f, 0.f};

    // staging: thread covers (row = tid>>3, slot = tid&7) and (row+32, same slot)
    int srow = tid >> 3;
    int sslot = tid & 7;
    int gslot = sslot ^ (srow & 7);          // (srow+32)&7 == srow&7
    const unsigned short* gA0 = A + (size_t)(tileM + srow) * K + gslot * 8;
    const unsigned short* gA1 = A + (size_t)(tileM + 32 + srow) * K + gslot * 8;
    const unsigned short* gB0 = B + (size_t)srow * K + gslot * 8;
    const unsigned short* gB1 = B + (size_t)(32 + srow) * K + gslot * 8;
    unsigned short* lA0 = As + tid * 8;
    unsigned short* lA1 = As + 2048 + tid * 8;
    unsigned short* lB0 = Bs + tid * 8;
    unsigned short* lB1 = Bs + 2048 + tid * 8;

    int fr = lane & 15;
    int kq = lane >> 4;

    for (int k0 = 0; k0 < K; k0 += 64) {
        gload_lds16(gA0, lA0); gload_lds16(gA1, lA1);
        gload_lds16(gB0, lB0); gload_lds16(gB1, lB1);
        gA0 += 64; gA1 += 64; gB0 += 64; gB1 += 64;
        __syncthreads();
        bf16x8 af[2][2], bfr[2][2];
#pragma unroll
        for (int m = 0; m < 2; ++m) {
            int row = wr * 32 + m * 16 + fr;
#pragma unroll
            for (int ks = 0; ks < 2; ++ks) {
                int sl = (ks * 4 + kq) ^ (row & 7);
                af[m][ks] = *(const bf16x8*)(As + row * 64 + sl * 8);
            }
        }
#pragma unroll
        for (int n = 0; n < 2; ++n) {
            int col = wc * 32 + n * 16 + fr;
#pragma unroll
            for (int ks = 0; ks < 2; ++ks) {
                int sl = (ks * 4 + kq) ^ (col & 7);
                bfr[n][ks] = *(const bf16x8*)(Bs + col * 64 + sl * 8);
            }
        }
#pragma unroll
        for (int m = 0; m < 2; ++m)
#pragma unroll
            for (int n = 0; n < 2; ++n)
#pragma unroll
                for (int ks = 0; ks < 2; ++ks)
                    acc[m][n] = __builtin_amdgcn_mfma_f32_16x16x32_bf16(
                        af[m][ks], bfr[n][ks], acc[m][n], 0, 0, 0);
        __syncthreads();
    }

    int crow0 = tileM + wr * 32;

    if (!isProj) {
        int ccol0 = bn * 64 + wc * 32;
        int head = bn >> 2;
        // colsum atomics
#pragma unroll
        for (int n = 0; n < 2; ++n) {
            float s = 0.f;
#pragma unroll
            for (int m = 0; m < 2; ++m)
#pragma unroll
                for (int q = 0; q < 4; ++q) s += acc[m][n][q];
            s += __shfl_xor(s, 16);
            s += __shfl_xor(s, 32);
            if (kq == 0)
                atomicAdd(colsum + ccol0 + n * 16 + fr, s);
        }
        // wh1/wh2 fused row-dots -> [node][4] layout
        float c1[2], c2[2];
#pragma unroll
        for (int n = 0; n < 2; ++n) {
            int j = (ccol0 + n * 16 + fr) & 255;
            c1[n] = av[head * 512 + j];
            c2[n] = av[head * 512 + 256 + j];
        }
#pragma unroll
        for (int m = 0; m < 2; ++m)
#pragma unroll
            for (int q = 0; q < 4; ++q) {
                float p1 = 0.f, p2 = 0.f;
#pragma unroll
                for (int n = 0; n < 2; ++n) {
                    p1 += acc[m][n][q] * c1[n];
                    p2 += acc[m][n][q] * c2[n];
                }
#pragma unroll
                for (int o = 1; o < 16; o <<= 1) {
                    p1 += __shfl_xor(p1, o);
                    p2 += __shfl_xor(p2, o);
                }
                if (fr == 0) {
                    int r = crow0 + m * 16 + kq * 4 + q;
                    atomicAdd(wh1 + r * 4 + head, p1);
                    atomicAdd(wh2 + r * 4 + head, p2);
                }
            }
        // bf16 C store, HEAD-MAJOR: Cbf[head][node][256]
#pragma unroll
        for (int m = 0; m < 2; ++m)
#pragma unroll
            for (int n = 0; n < 2; ++n) {
                int r0 = crow0 + m * 16 + kq * 4;
                int c  = ccol0 + n * 16 + fr;
                int j  = c & 255;
#pragma unroll
                for (int q = 0; q < 4; ++q)
                    Cbf[((size_t)head * NNODES + r0 + q) * 256 + j] = f2bf(acc[m][n][q]);
            }
    } else {
        int pcol0 = (bn - 16) * 64 + wc * 32;
#pragma unroll
        for (int m = 0; m < 2; ++m)
#pragma unroll
            for (int n = 0; n < 2; ++n) {
                int r0 = crow0 + m * 16 + kq * 4;
                int c  = pcol0 + n * 16 + fr;
                float bv = pb[c & 255];
#pragma unroll
                for (int q = 0; q < 4; ++q)
                    Cproj[(size_t)(r0 + q) * 256 + c] = acc[m][n][q] + bv;
            }
    }
}

// ---------------- per-row attention: 1 wave per row, 4 head-major passes ----------
// h_bf is [head][node][256]; each pass touches a 2MB slice (per-XCD L2-resident).
// No __syncthreads: all state is wave-local (LDS regions partitioned per wave).
__global__ __launch_bounds__(256) void row_attn(
    const unsigned short* __restrict__ h_bf, const float* __restrict__ wh1,
    const float* __restrict__ wh2, const float* __restrict__ colsum,
    const int* __restrict__ cnt, const int* __restrict__ cols,
    const float* __restrict__ bias, const float* __restrict__ prev,
    float* __restrict__ outp, unsigned short* __restrict__ out_bf, int N)
{
    int t = threadIdx.x;
    int wv = t >> 6;
    int lane = t & 63;
    int i = blockIdx.x * 4 + wv;          // wave-private row
    __shared__ int  colsS[4][MAXDEG];
    __shared__ f32x4 wS[4][MAXDEG];       // [row-in-block][k] -> 4 head weights
    int deg = cnt[i];
    if (deg > MAXDEG) deg = MAXDEG;

    float4 w1 = *(const float4*)(wh1 + i * 4);
    for (int k = lane; k < deg; k += 64) {
        int c = cols[i * MAXDEG + k];
        colsS[wv][k] = c;
        float4 w2 = *(const float4*)(wh2 + c * 4);
        float s0 = w1.x + w2.x, s1 = w1.y + w2.y, s2 = w1.z + w2.z, s3 = w1.w + w2.w;
        s0 = s0 > 0.f ? s0 : 0.2f * s0;
        s1 = s1 > 0.f ? s1 : 0.2f * s1;
        s2 = s2 > 0.f ? s2 : 0.2f * s2;
        s3 = s3 > 0.f ? s3 : 0.2f * s3;
        f32x4 w;
        w[0] = expf(s0) - 1.f; w[1] = expf(s1) - 1.f;
        w[2] = expf(s2) - 1.f; w[3] = expf(s3) - 1.f;
        wS[wv][k] = w;
    }
    // wave-local LDS produce->consume; compiler inserts lgkmcnt waits. No barrier:
    // each wave only reads its own wS/colsS rows.

    float fs0 = 0.f, fs1 = 0.f, fs2 = 0.f, fs3 = 0.f;
#pragma unroll
    for (int h = 0; h < NHEADS; ++h) {
        float a0 = 0.f, a1 = 0.f, a2 = 0.f, a3 = 0.f, wsum = 0.f;
        const unsigned short* hb = h_bf + ((size_t)h * NNODES) * 256 + lane * 4;
#pragma unroll 2
        for (int k = 0; k < deg; ++k) {
            float w = wS[wv][k][h];
            uint2 v = *(const uint2*)(hb + (size_t)colsS[wv][k] * 256);
            wsum += w;
            a0 += w * __uint_as_float(v.x << 16);
            a1 += w * __uint_as_float(v.x & 0xffff0000u);
            a2 += w * __uint_as_float(v.y << 16);
            a3 += w * __uint_as_float(v.y & 0xffff0000u);
        }
        float inv = 1.f / ((float)NNODES + wsum);
        float4 cs = *(const float4*)(colsum + h * 256 + lane * 4);
        float v0 = (cs.x + a0) * inv, v1 = (cs.y + a1) * inv;
        float v2 = (cs.z + a2) * inv, v3 = (cs.w + a3) * inv;
        v0 = v0 > 0.f ? v0 : 0.2f * v0;
        v1 = v1 > 0.f ? v1 : 0.2f * v1;
        v2 = v2 > 0.f ? v2 : 0.2f * v2;
        v3 = v3 > 0.f ? v3 : 0.2f * v3;
        float sq = v0 * v0 + v1 * v1 + v2 * v2 + v3 * v3;
#pragma unroll
        for (int o = 1; o < 64; o <<= 1) sq += __shfl_xor(sq, o);
        float rinv = 1.f / fmaxf(sqrtf(sq), 1e-12f);
        float4 bb = *(const float4*)(bias + h * 256 + lane * 4);
        fs0 += v0 * rinv + bb.x;
        fs1 += v1 * rinv + bb.y;
        fs2 += v2 * rinv + bb.z;
        fs3 += v3 * rinv + bb.w;
    }
    float4 pv = *(const float4*)(prev + (size_t)i * 256 + lane * 4);
    float o0 = fs0 * 0.25f + pv.x;
    float o1 = fs1 * 0.25f + pv.y;
    float o2 = fs2 * 0.25f + pv.z;
    float o3 = fs3 * 0.25f + pv.w;
    o0 = o0 > 0.f ? o0 : (expf(o0) - 1.f);
    o1 = o1 > 0.f ? o1 : (expf(o1) - 1.f);
    o2 = o2 > 0.f ? o2 : (expf(o2) - 1.f);
    o3 = o3 > 0.f ? o3 : (expf(o3) - 1.f);
    f32x4 ov; ov[0] = o0; ov[1] = o1; ov[2] = o2; ov[3] = o3;
    *(f32x4*)(outp + (size_t)i * 256 + lane * 4) = ov;
    us4 ob; ob.x = f2bf(o0); ob.y = f2bf(o1); ob.z = f2bf(o2); ob.w = f2bf(o3);
    *(us4*)(out_bf + (size_t)i * 256 + lane * 4) = ob;
}

extern "C" void kernel_launch(void* const* d_in, const int* in_sizes, int n_in,
                              void* d_out, int out_size, void* d_ws, size_t ws_size,
                              hipStream_t stream)
{
    const float* x  = (const float*)d_in[0];
    const int*   ei = (const int*)d_in[1];
    const float* W1 = (const float*)d_in[2];
    const float* a1 = (const float*)d_in[3];
    const float* b1 = (const float*)d_in[4];
    const float* Wk = (const float*)d_in[5];
    const float* ak = (const float*)d_in[6];
    const float* bk = (const float*)d_in[7];
    const float* pW = (const float*)d_in[8];
    const float* pb = (const float*)d_in[9];
    const int N = NNODES;
    const int E = in_sizes[1] / 2;
    const int* er = ei;
    const int* ec = ei + E;

    float* ws = (float*)d_ws;
    size_t off = 0;
    float* bufA    = ws + off; off += (size_t)N * 256;
    float* bufProj = ws + off; off += (size_t)N * 256;
    float* wh1     = ws + off; off += (size_t)NHEADS * N;   // [node][4]
    float* wh2     = ws + off; off += (size_t)NHEADS * N;   // [node][4]
    float* colsum  = ws + off; off += 1024;
    int*   cnt     = (int*)(ws + off); off += N;
    int*   cols    = (int*)(ws + off); off += (size_t)N * MAXDEG;
    unsigned int* bitmap = (unsigned int*)(ws + off); off += (size_t)N * N / 32;
    unsigned short* h_bf  = (unsigned short*)(ws + off); off += (size_t)N * 1024 / 2;  // [head][node][256]
    unsigned short* xb    = (unsigned short*)(ws + off); off += (size_t)N * 512 / 2;
    unsigned short* bufAb = (unsigned short*)(ws + off); off += (size_t)N * 256 / 2;
    unsigned short* Wt1   = (unsigned short*)(ws + off); off += (size_t)4 * 256 * 512 / 2;
    unsigned short* Wtk   = (unsigned short*)(ws + off); off += (size_t)12 * 256 * 256 / 2;
    unsigned short* pWt   = (unsigned short*)(ws + off); off += (size_t)256 * 512 / 2;

    hipMemsetAsync(cnt, 0, N * sizeof(int), stream);
    hipMemsetAsync(bitmap, 0, (size_t)N * N / 8, stream);
    build_csr<<<(E + 255) / 256, 256, 0, stream>>>(er, ec, bitmap, cnt, cols, E);

    cvt_bf16<<<(N * 512 / 4 + 255) / 256, 256, 0, stream>>>(x, xb, N * 512 / 4);
    transpose_w<<<dim3(16, 8, 1), 256, 0, stream>>>(pW, pWt, 512);
    transpose_w<<<dim3(16, 8, 4), 256, 0, stream>>>(W1, Wt1, 512);
    transpose_w<<<dim3(8, 8, 12), 256, 0, stream>>>(Wk, Wtk, 256);

    for (int l = 0; l < 4; ++l) {
        int K = (l == 0) ? 512 : 256;
        const unsigned short* Wt = (l == 0) ? Wt1 : Wtk + (size_t)(l - 1) * 4 * 256 * 256;
        const float* av = (l == 0) ? a1 : ak + (size_t)(l - 1) * NHEADS * 512;
        const float* bv = (l == 0) ? b1 : bk + (size_t)(l - 1) * NHEADS * 256;
        const unsigned short* Ab = (l == 0) ? xb : bufAb;

        // zero wh1 | wh2 | colsum (contiguous) for the fused-epilogue atomics
        hipMemsetAsync(wh1, 0, (2 * NHEADS * N + 1024) * sizeof(float), stream);
        if (l == 0)
            gemm_mfma<1><<<dim3(20, 64), 256, 0, stream>>>(
                Ab, Wt, pWt, pb, bufProj, h_bf, av, wh1, wh2, colsum, K);
        else
            gemm_mfma<0><<<dim3(16, 64), 256, 0, stream>>>(
                Ab, Wt, nullptr, nullptr, nullptr, h_bf, av, wh1, wh2, colsum, K);

        const float* prev = (l == 0) ? bufProj : bufA;
        float* outp = (l == 3) ? (float*)d_out : bufA;
        row_attn<<<N / 4, 256, 0, stream>>>(h_bf, wh1, wh2, colsum, cnt, cols, bv, prev, outp, bufAb, N);
    }
}

// Round 8
// 293.436 us; speedup vs baseline: 1.1006x; 1.1006x over previous
//
#include <hip/hip_runtime.h>
#include <hip/hip_bf16.h>
#include <math.h>

#define NNODES 4096
#define NHEADS 4
#define MAXDEG 128

typedef __attribute__((ext_vector_type(8))) short  bf16x8;
typedef __attribute__((ext_vector_type(4))) float  f32x4;
typedef __attribute__((ext_vector_type(4))) unsigned short us4;

__device__ __forceinline__ unsigned short f2bf(float v) {
    unsigned int x = __float_as_uint(v);
    unsigned int r = (x + 0x7fffu + ((x >> 16) & 1u)) >> 16;   // RNE
    return (unsigned short)r;
}

__device__ __forceinline__ void gload_lds16(const unsigned short* g, unsigned short* l) {
    __builtin_amdgcn_global_load_lds(
        (const __attribute__((address_space(1))) unsigned int*)(g),
        (__attribute__((address_space(3))) unsigned int*)(l), 16, 0, 0);
}

// ---------------- CSR build with bitmap dedupe ----------------
__global__ __launch_bounds__(256) void build_csr(
    const int* __restrict__ er, const int* __restrict__ ec,
    unsigned int* __restrict__ bitmap, int* __restrict__ cnt,
    int* __restrict__ cols, int E)
{
    int e = blockIdx.x * 256 + threadIdx.x;
    if (e >= E) return;
    int r = er[e], c = ec[e];
    unsigned int idx = ((unsigned int)r << 12) | (unsigned int)c;
    unsigned int bit = 1u << (idx & 31);
    unsigned int old = atomicOr(&bitmap[idx >> 5], bit);
    if (!(old & bit)) {
        int slot = atomicAdd(&cnt[r], 1);
        if (slot < MAXDEG) cols[r * MAXDEG + slot] = c;
    }
}

// ---------------- fp32 -> bf16 elementwise (vectorized) ----------------
__global__ __launch_bounds__(256) void cvt_bf16(
    const float* __restrict__ in, unsigned short* __restrict__ out, int n4)
{
    int i = blockIdx.x * 256 + threadIdx.x;
    if (i >= n4) return;
    float4 v = *(const float4*)(in + (size_t)i * 4);
    us4 o; o.x = f2bf(v.x); o.y = f2bf(v.y); o.z = f2bf(v.z); o.w = f2bf(v.w);
    *(us4*)(out + (size_t)i * 4) = o;
}

// ---------------- W[h][k][j] fp32 -> Wt[h*256+j][K] bf16 (tiled transpose) ----------------
__global__ __launch_bounds__(256) void transpose_w(
    const float* __restrict__ W, unsigned short* __restrict__ Wt, int K)
{
    __shared__ float tile[32][33];
    int k0 = blockIdx.x * 32;
    int j0 = blockIdx.y * 32;
    int h  = blockIdx.z;
    int tj = threadIdx.x & 31;
    int tk = threadIdx.x >> 5;
#pragma unroll
    for (int it = 0; it < 4; ++it) {
        int kl = tk + it * 8;
        tile[kl][tj] = W[(size_t)h * K * 256 + (size_t)(k0 + kl) * 256 + j0 + tj];
    }
    __syncthreads();
#pragma unroll
    for (int it = 0; it < 4; ++it) {
        int jl = tk + it * 8;
        Wt[(size_t)(h * 256 + j0 + jl) * K + k0 + tj] = f2bf(tile[tj][jl]);
    }
}

// ---------------- bf16 MFMA GEMM, 64x64 tile, BK=64, single-buffer ----------
// Main blocks (bn<16): HEAD-MAJOR bf16 h store + fused wh1/wh2 ([node][4]) + colsum.
// Proj blocks (bn>=16, HASPROJ only): fp32 + bias into Cproj (stride 256).
template <int HASPROJ>
__global__ __launch_bounds__(256) void gemm_mfma(
    const unsigned short* __restrict__ A, const unsigned short* __restrict__ Bt,
    const unsigned short* __restrict__ pBt, const float* __restrict__ pb,
    float* __restrict__ Cproj, unsigned short* __restrict__ Cbf,
    const float* __restrict__ av, float* __restrict__ wh1, float* __restrict__ wh2,
    float* __restrict__ colsum, int K)
{
    __shared__ unsigned short As[64 * 64];   // 64 rows x 128B
    __shared__ unsigned short Bs[64 * 64];
    int tid = threadIdx.x;
    int lane = tid & 63;
    int wave = tid >> 6;
    int wr = wave >> 1, wc = wave & 1;
    int bn = blockIdx.x, bm = blockIdx.y;
    int tileM = bm * 64;
    bool isProj = HASPROJ && (bn >= 16);
    const unsigned short* B = isProj ? pBt + (size_t)(bn - 16) * 64 * K
                                     : Bt + (size_t)bn * 64 * K;

    f32x4 acc[2][2];
#pragma unroll
    for (int m = 0; m < 2; ++m)
#pragma unroll
        for (int n = 0; n < 2; ++n) acc[m][n] = (f32x4){0.f, 0.f, 0.f, 0.f};

    // staging: thread covers (row = tid>>3, slot = tid&7) and (row+32, same slot)
    int srow = tid >> 3;
    int sslot = tid & 7;
    int gslot = sslot ^ (srow & 7);          // (srow+32)&7 == srow&7
    const unsigned short* gA0 = A + (size_t)(tileM + srow) * K + gslot * 8;
    const unsigned short* gA1 = A + (size_t)(tileM + 32 + srow) * K + gslot * 8;
    const unsigned short* gB0 = B + (size_t)srow * K + gslot * 8;
    const unsigned short* gB1 = B + (size_t)(32 + srow) * K + gslot * 8;
    unsigned short* lA0 = As + tid * 8;
    unsigned short* lA1 = As + 2048 + tid * 8;
    unsigned short* lB0 = Bs + tid * 8;
    unsigned short* lB1 = Bs + 2048 + tid * 8;

    int fr = lane & 15;
    int kq = lane >> 4;

    for (int k0 = 0; k0 < K; k0 += 64) {
        gload_lds16(gA0, lA0); gload_lds16(gA1, lA1);
        gload_lds16(gB0, lB0); gload_lds16(gB1, lB1);
        gA0 += 64; gA1 += 64; gB0 += 64; gB1 += 64;
        __syncthreads();
        bf16x8 af[2][2], bfr[2][2];
#pragma unroll
        for (int m = 0; m < 2; ++m) {
            int row = wr * 32 + m * 16 + fr;
#pragma unroll
            for (int ks = 0; ks < 2; ++ks) {
                int sl = (ks * 4 + kq) ^ (row & 7);
                af[m][ks] = *(const bf16x8*)(As + row * 64 + sl * 8);
            }
        }
#pragma unroll
        for (int n = 0; n < 2; ++n) {
            int col = wc * 32 + n * 16 + fr;
#pragma unroll
            for (int ks = 0; ks < 2; ++ks) {
                int sl = (ks * 4 + kq) ^ (col & 7);
                bfr[n][ks] = *(const bf16x8*)(Bs + col * 64 + sl * 8);
            }
        }
#pragma unroll
        for (int m = 0; m < 2; ++m)
#pragma unroll
            for (int n = 0; n < 2; ++n)
#pragma unroll
                for (int ks = 0; ks < 2; ++ks)
                    acc[m][n] = __builtin_amdgcn_mfma_f32_16x16x32_bf16(
                        af[m][ks], bfr[n][ks], acc[m][n], 0, 0, 0);
        __syncthreads();
    }

    int crow0 = tileM + wr * 32;

    if (!isProj) {
        int ccol0 = bn * 64 + wc * 32;
        int head = bn >> 2;
        // colsum atomics
#pragma unroll
        for (int n = 0; n < 2; ++n) {
            float s = 0.f;
#pragma unroll
            for (int m = 0; m < 2; ++m)
#pragma unroll
                for (int q = 0; q < 4; ++q) s += acc[m][n][q];
            s += __shfl_xor(s, 16);
            s += __shfl_xor(s, 32);
            if (kq == 0)
                atomicAdd(colsum + ccol0 + n * 16 + fr, s);
        }
        // wh1/wh2 fused row-dots -> [node][4] layout
        float c1[2], c2[2];
#pragma unroll
        for (int n = 0; n < 2; ++n) {
            int j = (ccol0 + n * 16 + fr) & 255;
            c1[n] = av[head * 512 + j];
            c2[n] = av[head * 512 + 256 + j];
        }
#pragma unroll
        for (int m = 0; m < 2; ++m)
#pragma unroll
            for (int q = 0; q < 4; ++q) {
                float p1 = 0.f, p2 = 0.f;
#pragma unroll
                for (int n = 0; n < 2; ++n) {
                    p1 += acc[m][n][q] * c1[n];
                    p2 += acc[m][n][q] * c2[n];
                }
#pragma unroll
                for (int o = 1; o < 16; o <<= 1) {
                    p1 += __shfl_xor(p1, o);
                    p2 += __shfl_xor(p2, o);
                }
                if (fr == 0) {
                    int r = crow0 + m * 16 + kq * 4 + q;
                    atomicAdd(wh1 + r * 4 + head, p1);
                    atomicAdd(wh2 + r * 4 + head, p2);
                }
            }
        // bf16 C store, HEAD-MAJOR: Cbf[head][node][256]
#pragma unroll
        for (int m = 0; m < 2; ++m)
#pragma unroll
            for (int n = 0; n < 2; ++n) {
                int r0 = crow0 + m * 16 + kq * 4;
                int c  = ccol0 + n * 16 + fr;
                int j  = c & 255;
#pragma unroll
                for (int q = 0; q < 4; ++q)
                    Cbf[((size_t)head * NNODES + r0 + q) * 256 + j] = f2bf(acc[m][n][q]);
            }
    } else {
        int pcol0 = (bn - 16) * 64 + wc * 32;
#pragma unroll
        for (int m = 0; m < 2; ++m)
#pragma unroll
            for (int n = 0; n < 2; ++n) {
                int r0 = crow0 + m * 16 + kq * 4;
                int c  = pcol0 + n * 16 + fr;
                float bv = pb[c & 255];
#pragma unroll
                for (int q = 0; q < 4; ++q)
                    Cproj[(size_t)(r0 + q) * 256 + c] = acc[m][n][q] + bv;
            }
    }
}

// ---------------- per-(head,row) attention gather ----------------
// grid = 4096 blocks, HEAD-MAJOR order: h = bx>>10, rows = (bx&1023)*4 .. +3.
// One wave per (head,row): 32-iter gather over a 2MB L2-resident slice.
// Writes per-head partials hpart[h][row][256] (f32); finalize combines.
__global__ __launch_bounds__(256) void row_attn(
    const unsigned short* __restrict__ h_bf, const float* __restrict__ wh1,
    const float* __restrict__ wh2, const float* __restrict__ colsum,
    const int* __restrict__ cnt, const int* __restrict__ cols,
    const float* __restrict__ bias, float* __restrict__ hpart, int N)
{
    int t = threadIdx.x;
    int wv = t >> 6;
    int lane = t & 63;
    int bx = blockIdx.x;
    int h = bx >> 10;                       // 1024 blocks per head, dispatched together
    int i = ((bx & 1023) << 2) + wv;        // wave-private row
    __shared__ int   colsS[4][MAXDEG];
    __shared__ float wS[4][MAXDEG];
    int deg = cnt[i];
    if (deg > MAXDEG) deg = MAXDEG;

    float w1 = wh1[i * 4 + h];
    for (int k = lane; k < deg; k += 64) {
        int c = cols[i * MAXDEG + k];
        colsS[wv][k] = c;
        float s = w1 + wh2[c * 4 + h];
        s = s > 0.f ? s : 0.2f * s;
        wS[wv][k] = expf(s) - 1.f;
    }
    // wave-local LDS produce->consume; no barrier (each wave reads only its rows)

    float a0 = 0.f, a1 = 0.f, a2 = 0.f, a3 = 0.f, wsum = 0.f;
    const unsigned short* hb = h_bf + ((size_t)h * N) * 256 + lane * 4;
#pragma unroll 2
    for (int k = 0; k < deg; ++k) {
        float w = wS[wv][k];
        uint2 v = *(const uint2*)(hb + (size_t)colsS[wv][k] * 256);
        wsum += w;
        a0 += w * __uint_as_float(v.x << 16);
        a1 += w * __uint_as_float(v.x & 0xffff0000u);
        a2 += w * __uint_as_float(v.y << 16);
        a3 += w * __uint_as_float(v.y & 0xffff0000u);
    }
    float inv = 1.f / ((float)NNODES + wsum);
    float4 cs = *(const float4*)(colsum + h * 256 + lane * 4);
    float v0 = (cs.x + a0) * inv, v1 = (cs.y + a1) * inv;
    float v2 = (cs.z + a2) * inv, v3 = (cs.w + a3) * inv;
    v0 = v0 > 0.f ? v0 : 0.2f * v0;
    v1 = v1 > 0.f ? v1 : 0.2f * v1;
    v2 = v2 > 0.f ? v2 : 0.2f * v2;
    v3 = v3 > 0.f ? v3 : 0.2f * v3;
    float sq = v0 * v0 + v1 * v1 + v2 * v2 + v3 * v3;
#pragma unroll
    for (int o = 1; o < 64; o <<= 1) sq += __shfl_xor(sq, o);
    float rinv = 1.f / fmaxf(sqrtf(sq), 1e-12f);
    float4 bb = *(const float4*)(bias + h * 256 + lane * 4);
    f32x4 pv;
    pv[0] = v0 * rinv + bb.x; pv[1] = v1 * rinv + bb.y;
    pv[2] = v2 * rinv + bb.z; pv[3] = v3 * rinv + bb.w;
    *(f32x4*)(hpart + ((size_t)h * N + i) * 256 + lane * 4) = pv;
}

// ---------------- finalize: head-mean + residual + elu (+ bf16 copy) ----------------
__global__ __launch_bounds__(256) void finalize(
    const float* __restrict__ hpart, const float* __restrict__ prev,
    float* __restrict__ outp, unsigned short* __restrict__ out_bf, int N)
{
    int idx = blockIdx.x * 256 + threadIdx.x;      // float4 units; total N*64
    size_t o4 = (size_t)idx * 4;
    const size_t stride = (size_t)N * 256;
    float4 p0 = *(const float4*)(hpart + o4);
    float4 p1 = *(const float4*)(hpart + stride + o4);
    float4 p2 = *(const float4*)(hpart + 2 * stride + o4);
    float4 p3 = *(const float4*)(hpart + 3 * stride + o4);
    float4 pr = *(const float4*)(prev + o4);
    float o0 = (p0.x + p1.x + p2.x + p3.x) * 0.25f + pr.x;
    float o1 = (p0.y + p1.y + p2.y + p3.y) * 0.25f + pr.y;
    float o2 = (p0.z + p1.z + p2.z + p3.z) * 0.25f + pr.z;
    float o3 = (p0.w + p1.w + p2.w + p3.w) * 0.25f + pr.w;
    o0 = o0 > 0.f ? o0 : (expf(o0) - 1.f);
    o1 = o1 > 0.f ? o1 : (expf(o1) - 1.f);
    o2 = o2 > 0.f ? o2 : (expf(o2) - 1.f);
    o3 = o3 > 0.f ? o3 : (expf(o3) - 1.f);
    f32x4 ov; ov[0] = o0; ov[1] = o1; ov[2] = o2; ov[3] = o3;
    *(f32x4*)(outp + o4) = ov;
    us4 ob; ob.x = f2bf(o0); ob.y = f2bf(o1); ob.z = f2bf(o2); ob.w = f2bf(o3);
    *(us4*)(out_bf + o4) = ob;
}

extern "C" void kernel_launch(void* const* d_in, const int* in_sizes, int n_in,
                              void* d_out, int out_size, void* d_ws, size_t ws_size,
                              hipStream_t stream)
{
    const float* x  = (const float*)d_in[0];
    const int*   ei = (const int*)d_in[1];
    const float* W1 = (const float*)d_in[2];
    const float* a1 = (const float*)d_in[3];
    const float* b1 = (const float*)d_in[4];
    const float* Wk = (const float*)d_in[5];
    const float* ak = (const float*)d_in[6];
    const float* bk = (const float*)d_in[7];
    const float* pW = (const float*)d_in[8];
    const float* pb = (const float*)d_in[9];
    const int N = NNODES;
    const int E = in_sizes[1] / 2;
    const int* er = ei;
    const int* ec = ei + E;

    float* ws = (float*)d_ws;
    size_t off = 0;
    float* bufA    = ws + off; off += (size_t)N * 256;
    float* bufProj = ws + off; off += (size_t)N * 256;
    float* hpart   = ws + off; off += (size_t)NHEADS * N * 256;   // [head][node][256]
    float* wh1     = ws + off; off += (size_t)NHEADS * N;   // [node][4]
    float* wh2     = ws + off; off += (size_t)NHEADS * N;   // [node][4]
    float* colsum  = ws + off; off += 1024;
    int*   cnt     = (int*)(ws + off); off += N;
    int*   cols    = (int*)(ws + off); off += (size_t)N * MAXDEG;
    unsigned int* bitmap = (unsigned int*)(ws + off); off += (size_t)N * N / 32;
    unsigned short* h_bf  = (unsigned short*)(ws + off); off += (size_t)N * 1024 / 2;  // [head][node][256]
    unsigned short* xb    = (unsigned short*)(ws + off); off += (size_t)N * 512 / 2;
    unsigned short* bufAb = (unsigned short*)(ws + off); off += (size_t)N * 256 / 2;
    unsigned short* Wt1   = (unsigned short*)(ws + off); off += (size_t)4 * 256 * 512 / 2;
    unsigned short* Wtk   = (unsigned short*)(ws + off); off += (size_t)12 * 256 * 256 / 2;
    unsigned short* pWt   = (unsigned short*)(ws + off); off += (size_t)256 * 512 / 2;

    hipMemsetAsync(cnt, 0, N * sizeof(int), stream);
    hipMemsetAsync(bitmap, 0, (size_t)N * N / 8, stream);
    build_csr<<<(E + 255) / 256, 256, 0, stream>>>(er, ec, bitmap, cnt, cols, E);

    cvt_bf16<<<(N * 512 / 4 + 255) / 256, 256, 0, stream>>>(x, xb, N * 512 / 4);
    transpose_w<<<dim3(16, 8, 1), 256, 0, stream>>>(pW, pWt, 512);
    transpose_w<<<dim3(16, 8, 4), 256, 0, stream>>>(W1, Wt1, 512);
    transpose_w<<<dim3(8, 8, 12), 256, 0, stream>>>(Wk, Wtk, 256);

    for (int l = 0; l < 4; ++l) {
        int K = (l == 0) ? 512 : 256;
        const unsigned short* Wt = (l == 0) ? Wt1 : Wtk + (size_t)(l - 1) * 4 * 256 * 256;
        const float* av = (l == 0) ? a1 : ak + (size_t)(l - 1) * NHEADS * 512;
        const float* bv = (l == 0) ? b1 : bk + (size_t)(l - 1) * NHEADS * 256;
        const unsigned short* Ab = (l == 0) ? xb : bufAb;

        // zero wh1 | wh2 | colsum (contiguous) for the fused-epilogue atomics
        hipMemsetAsync(wh1, 0, (2 * NHEADS * N + 1024) * sizeof(float), stream);
        if (l == 0)
            gemm_mfma<1><<<dim3(20, 64), 256, 0, stream>>>(
                Ab, Wt, pWt, pb, bufProj, h_bf, av, wh1, wh2, colsum, K);
        else
            gemm_mfma<0><<<dim3(16, 64), 256, 0, stream>>>(
                Ab, Wt, nullptr, nullptr, nullptr, h_bf, av, wh1, wh2, colsum, K);

        row_attn<<<4096, 256, 0, stream>>>(h_bf, wh1, wh2, colsum, cnt, cols, bv, hpart, N);

        const float* prev = (l == 0) ? bufProj : bufA;
        float* outp = (l == 3) ? (float*)d_out : bufA;
        finalize<<<N * 64 / 256, 256, 0, stream>>>(hpart, prev, outp, bufAb, N);
    }
}

// Round 9
// 228.607 us; speedup vs baseline: 1.4128x; 1.2836x over previous
//
#include <hip/hip_runtime.h>
#include <hip/hip_bf16.h>
#include <math.h>

#define NNODES 4096
#define NHEADS 4
#define MAXDEG 128

typedef __attribute__((ext_vector_type(8))) short  bf16x8;
typedef __attribute__((ext_vector_type(4))) float  f32x4;
typedef __attribute__((ext_vector_type(4))) unsigned short us4;

__device__ __forceinline__ unsigned short f2bf(float v) {
    unsigned int x = __float_as_uint(v);
    unsigned int r = (x + 0x7fffu + ((x >> 16) & 1u)) >> 16;   // RNE
    return (unsigned short)r;
}

__device__ __forceinline__ void gload_lds16(const unsigned short* g, unsigned short* l) {
    __builtin_amdgcn_global_load_lds(
        (const __attribute__((address_space(1))) unsigned int*)(g),
        (__attribute__((address_space(3))) unsigned int*)(l), 16, 0, 0);
}

// ---------------- CSR build with bitmap dedupe ----------------
__global__ __launch_bounds__(256) void build_csr(
    const int* __restrict__ er, const int* __restrict__ ec,
    unsigned int* __restrict__ bitmap, int* __restrict__ cnt,
    int* __restrict__ cols, int E)
{
    int e = blockIdx.x * 256 + threadIdx.x;
    if (e >= E) return;
    int r = er[e], c = ec[e];
    unsigned int idx = ((unsigned int)r << 12) | (unsigned int)c;
    unsigned int bit = 1u << (idx & 31);
    unsigned int old = atomicOr(&bitmap[idx >> 5], bit);
    if (!(old & bit)) {
        int slot = atomicAdd(&cnt[r], 1);
        if (slot < MAXDEG) cols[r * MAXDEG + slot] = c;
    }
}

// ---------------- fp32 -> bf16 elementwise (vectorized) ----------------
__global__ __launch_bounds__(256) void cvt_bf16(
    const float* __restrict__ in, unsigned short* __restrict__ out, int n4)
{
    int i = blockIdx.x * 256 + threadIdx.x;
    if (i >= n4) return;
    float4 v = *(const float4*)(in + (size_t)i * 4);
    us4 o; o.x = f2bf(v.x); o.y = f2bf(v.y); o.z = f2bf(v.z); o.w = f2bf(v.w);
    *(us4*)(out + (size_t)i * 4) = o;
}

// ---------------- W[h][k][j] fp32 -> Wt[h*256+j][K] bf16 (tiled transpose) ----------------
__global__ __launch_bounds__(256) void transpose_w(
    const float* __restrict__ W, unsigned short* __restrict__ Wt, int K)
{
    __shared__ float tile[32][33];
    int k0 = blockIdx.x * 32;
    int j0 = blockIdx.y * 32;
    int h  = blockIdx.z;
    int tj = threadIdx.x & 31;
    int tk = threadIdx.x >> 5;
#pragma unroll
    for (int it = 0; it < 4; ++it) {
        int kl = tk + it * 8;
        tile[kl][tj] = W[(size_t)h * K * 256 + (size_t)(k0 + kl) * 256 + j0 + tj];
    }
    __syncthreads();
#pragma unroll
    for (int it = 0; it < 4; ++it) {
        int jl = tk + it * 8;
        Wt[(size_t)(h * 256 + j0 + jl) * K + k0 + tj] = f2bf(tile[tj][jl]);
    }
}

// ---------------- bf16 MFMA GEMM, 64x64 tile, BK=128 (3 barriers @K=256) ------
// Main blocks (bn<16): node-major bf16 h store + fused wh1/wh2 (head-major) + colsum.
// Proj blocks (bn>=16, HASPROJ only): fp32 + bias into Cproj (stride 256).
template <int HASPROJ>
__global__ __launch_bounds__(256) void gemm_mfma(
    const unsigned short* __restrict__ A, const unsigned short* __restrict__ Bt,
    const unsigned short* __restrict__ pBt, const float* __restrict__ pb,
    float* __restrict__ Cproj, unsigned short* __restrict__ Cbf,
    const float* __restrict__ av, float* __restrict__ wh1, float* __restrict__ wh2,
    float* __restrict__ colsum, int K)
{
    __shared__ unsigned short As[64 * 128];   // 64 rows x 256B = 16KB
    __shared__ unsigned short Bs[64 * 128];
    int tid = threadIdx.x;
    int lane = tid & 63;
    int wave = tid >> 6;
    int wr = wave >> 1, wc = wave & 1;
    int bn = blockIdx.x, bm = blockIdx.y;
    int tileM = bm * 64;
    bool isProj = HASPROJ && (bn >= 16);
    const unsigned short* B = isProj ? pBt + (size_t)(bn - 16) * 64 * K
                                     : Bt + (size_t)bn * 64 * K;

    f32x4 acc[2][2];
#pragma unroll
    for (int m = 0; m < 2; ++m)
#pragma unroll
        for (int n = 0; n < 2; ++n) acc[m][n] = (f32x4){0.f, 0.f, 0.f, 0.f};

    // staging geometry: round r covers rows r*16..r*16+15; thread -> (rowr = tid>>4,
    // slot = tid&15). Linear LDS dest; global source slot XOR'd (rule: both-sides swizzle).
    int rowr  = tid >> 4;                    // 0..15
    int gslot = (tid & 15) ^ (rowr & 7);     // row&7 constant across rounds (+16 rows)
    const unsigned short* gA = A + (size_t)(tileM + rowr) * K + gslot * 8;
    const unsigned short* gB = B + (size_t)rowr * K + gslot * 8;
    unsigned short* lA = As + tid * 8;       // + r*2048 per round (4KB)
    unsigned short* lB = Bs + tid * 8;

    int fr = lane & 15;
    int kq = lane >> 4;
    int nsteps = K >> 7;                     // 2 (K=256) or 4 (K=512)

    // per-m/n fragment row bases
    int arow[2], brow[2];
#pragma unroll
    for (int m = 0; m < 2; ++m) arow[m] = wr * 32 + m * 16 + fr;
#pragma unroll
    for (int n = 0; n < 2; ++n) brow[n] = wc * 32 + n * 16 + fr;

    for (int t = 0; t < nsteps; ++t) {
#pragma unroll
        for (int r = 0; r < 4; ++r) {
            gload_lds16(gA + (size_t)r * 16 * K, lA + r * 2048);
            gload_lds16(gB + (size_t)r * 16 * K, lB + r * 2048);
        }
        gA += 128; gB += 128;
        __syncthreads();                      // drain staged loads
#pragma unroll
        for (int ks = 0; ks < 4; ++ks) {      // 4 k-slices of 32
            bf16x8 af[2], bfv[2];
#pragma unroll
            for (int m = 0; m < 2; ++m) {
                int sl = ((ks * 4 + kq) ^ (arow[m] & 7)) * 8;
                af[m] = *(const bf16x8*)(As + arow[m] * 128 + sl);
            }
#pragma unroll
            for (int n = 0; n < 2; ++n) {
                int sl = ((ks * 4 + kq) ^ (brow[n] & 7)) * 8;
                bfv[n] = *(const bf16x8*)(Bs + brow[n] * 128 + sl);
            }
#pragma unroll
            for (int m = 0; m < 2; ++m)
#pragma unroll
                for (int n = 0; n < 2; ++n)
                    acc[m][n] = __builtin_amdgcn_mfma_f32_16x16x32_bf16(
                        af[m], bfv[n], acc[m][n], 0, 0, 0);
        }
        if (t + 1 < nsteps) __syncthreads();  // protect LDS rewrite
    }

    int crow0 = tileM + wr * 32;

    if (!isProj) {
        int ccol0 = bn * 64 + wc * 32;
        int head = bn >> 2;
        // colsum atomics
#pragma unroll
        for (int n = 0; n < 2; ++n) {
            float s = 0.f;
#pragma unroll
            for (int m = 0; m < 2; ++m)
#pragma unroll
                for (int q = 0; q < 4; ++q) s += acc[m][n][q];
            s += __shfl_xor(s, 16);
            s += __shfl_xor(s, 32);
            if (kq == 0)
                atomicAdd(colsum + ccol0 + n * 16 + fr, s);
        }
        // wh1/wh2 fused row-dots (head-major layout)
        float c1[2], c2[2];
#pragma unroll
        for (int n = 0; n < 2; ++n) {
            int j = (ccol0 + n * 16 + fr) & 255;
            c1[n] = av[head * 512 + j];
            c2[n] = av[head * 512 + 256 + j];
        }
#pragma unroll
        for (int m = 0; m < 2; ++m)
#pragma unroll
            for (int q = 0; q < 4; ++q) {
                float p1 = 0.f, p2 = 0.f;
#pragma unroll
                for (int n = 0; n < 2; ++n) {
                    p1 += acc[m][n][q] * c1[n];
                    p2 += acc[m][n][q] * c2[n];
                }
#pragma unroll
                for (int o = 1; o < 16; o <<= 1) {
                    p1 += __shfl_xor(p1, o);
                    p2 += __shfl_xor(p2, o);
                }
                if (fr == 0) {
                    int r = crow0 + m * 16 + kq * 4 + q;
                    atomicAdd(wh1 + head * NNODES + r, p1);
                    atomicAdd(wh2 + head * NNODES + r, p2);
                }
            }
        // bf16 C store, node-major (stride 1024)
#pragma unroll
        for (int m = 0; m < 2; ++m)
#pragma unroll
            for (int n = 0; n < 2; ++n) {
                int r0 = crow0 + m * 16 + kq * 4;
                int c  = ccol0 + n * 16 + fr;
#pragma unroll
                for (int q = 0; q < 4; ++q)
                    Cbf[(size_t)(r0 + q) * 1024 + c] = f2bf(acc[m][n][q]);
            }
    } else {
        int pcol0 = (bn - 16) * 64 + wc * 32;
#pragma unroll
        for (int m = 0; m < 2; ++m)
#pragma unroll
            for (int n = 0; n < 2; ++n) {
                int r0 = crow0 + m * 16 + kq * 4;
                int c  = pcol0 + n * 16 + fr;
                float bv = pb[c & 255];
#pragma unroll
                for (int q = 0; q < 4; ++q)
                    Cproj[(size_t)(r0 + q) * 256 + c] = acc[m][n][q] + bv;
            }
    }
}

// ---------------- per-row attention: all 4 heads in one gather pass (232us cfg) ----
// wave h = head h; lane f covers features 4f..4f+3 (uint2 = 4 bf16 per neighbor).
__global__ __launch_bounds__(256) void row_attn(
    const unsigned short* __restrict__ h_bf, const float* __restrict__ wh1,
    const float* __restrict__ wh2, const float* __restrict__ colsum,
    const int* __restrict__ cnt, const int* __restrict__ cols,
    const float* __restrict__ bias, const float* __restrict__ prev,
    float* __restrict__ outp, unsigned short* __restrict__ out_bf, int N)
{
    int i = blockIdx.x;
    int t = threadIdx.x;
    int h = t >> 6, f = t & 63;
    __shared__ int colsS[MAXDEG];
    __shared__ float wS[4][MAXDEG];
    __shared__ float fsum[1024];
    int deg = cnt[i];
    if (deg > MAXDEG) deg = MAXDEG;
    if (t < deg) colsS[t] = cols[i * MAXDEG + t];
    __syncthreads();

    {   // edge weights for all 4 heads: 2 head-pairs x 128 threads
        int k = t & 127;
        int hh0 = t >> 7;
#pragma unroll
        for (int p = 0; p < 2; ++p) {
            int hh = 2 * p + hh0;
            if (k < deg) {
                float s = wh1[hh * N + i] + wh2[hh * N + colsS[k]];
                s = s > 0.f ? s : 0.2f * s;
                wS[hh][k] = expf(s) - 1.f;
            }
        }
    }
    __syncthreads();

    float a0 = 0.f, a1 = 0.f, a2 = 0.f, a3 = 0.f, wsum = 0.f;
    const unsigned short* hb = h_bf + h * 256 + f * 4;
    for (int k = 0; k < deg; ++k) {
        float w = wS[h][k];
        uint2 v = *(const uint2*)(hb + (size_t)colsS[k] * 1024);
        wsum += w;
        a0 += w * __uint_as_float(v.x << 16);
        a1 += w * __uint_as_float(v.x & 0xffff0000u);
        a2 += w * __uint_as_float(v.y << 16);
        a3 += w * __uint_as_float(v.y & 0xffff0000u);
    }
    float inv = 1.f / ((float)NNODES + wsum);
    float4 cs = *(const float4*)(colsum + h * 256 + f * 4);
    float v0 = (cs.x + a0) * inv, v1 = (cs.y + a1) * inv;
    float v2 = (cs.z + a2) * inv, v3 = (cs.w + a3) * inv;
    v0 = v0 > 0.f ? v0 : 0.2f * v0;
    v1 = v1 > 0.f ? v1 : 0.2f * v1;
    v2 = v2 > 0.f ? v2 : 0.2f * v2;
    v3 = v3 > 0.f ? v3 : 0.2f * v3;
    float sq = v0 * v0 + v1 * v1 + v2 * v2 + v3 * v3;
#pragma unroll
    for (int o = 1; o < 64; o <<= 1) sq += __shfl_xor(sq, o);
    float rinv = 1.f / fmaxf(sqrtf(sq), 1e-12f);
    float4 bb = *(const float4*)(bias + h * 256 + f * 4);
    f32x4 fv;
    fv[0] = v0 * rinv + bb.x; fv[1] = v1 * rinv + bb.y;
    fv[2] = v2 * rinv + bb.z; fv[3] = v3 * rinv + bb.w;
    *(f32x4*)(fsum + h * 256 + f * 4) = fv;
    __syncthreads();
    float o = (fsum[t] + fsum[256 + t] + fsum[512 + t] + fsum[768 + t]) * 0.25f
              + prev[(size_t)i * 256 + t];
    o = o > 0.f ? o : (expf(o) - 1.f);
    outp[(size_t)i * 256 + t] = o;
    out_bf[(size_t)i * 256 + t] = f2bf(o);
}

extern "C" void kernel_launch(void* const* d_in, const int* in_sizes, int n_in,
                              void* d_out, int out_size, void* d_ws, size_t ws_size,
                              hipStream_t stream)
{
    const float* x  = (const float*)d_in[0];
    const int*   ei = (const int*)d_in[1];
    const float* W1 = (const float*)d_in[2];
    const float* a1 = (const float*)d_in[3];
    const float* b1 = (const float*)d_in[4];
    const float* Wk = (const float*)d_in[5];
    const float* ak = (const float*)d_in[6];
    const float* bk = (const float*)d_in[7];
    const float* pW = (const float*)d_in[8];
    const float* pb = (const float*)d_in[9];
    const int N = NNODES;
    const int E = in_sizes[1] / 2;
    const int* er = ei;
    const int* ec = ei + E;

    const size_t WHSZ = (size_t)2 * NHEADS * N + 1024;   // wh1 | wh2 | colsum per layer

    float* ws = (float*)d_ws;
    size_t off = 0;
    float* bufA    = ws + off; off += (size_t)N * 256;
    float* bufProj = ws + off; off += (size_t)N * 256;
    float* whall   = ws + off; off += 4 * WHSZ;          // 4 layers, zeroed once
    int*   cnt     = (int*)(ws + off); off += N;
    int*   cols    = (int*)(ws + off); off += (size_t)N * MAXDEG;
    unsigned int* bitmap = (unsigned int*)(ws + off); off += (size_t)N * N / 32;
    unsigned short* h_bf  = (unsigned short*)(ws + off); off += (size_t)N * 1024 / 2;  // [node][1024]
    unsigned short* xb    = (unsigned short*)(ws + off); off += (size_t)N * 512 / 2;
    unsigned short* bufAb = (unsigned short*)(ws + off); off += (size_t)N * 256 / 2;
    unsigned short* Wt1   = (unsigned short*)(ws + off); off += (size_t)4 * 256 * 512 / 2;
    unsigned short* Wtk   = (unsigned short*)(ws + off); off += (size_t)12 * 256 * 256 / 2;
    unsigned short* pWt   = (unsigned short*)(ws + off); off += (size_t)256 * 512 / 2;

    hipMemsetAsync(cnt, 0, N * sizeof(int), stream);
    hipMemsetAsync(bitmap, 0, (size_t)N * N / 8, stream);
    hipMemsetAsync(whall, 0, 4 * WHSZ * sizeof(float), stream);   // all layers' wh/colsum
    build_csr<<<(E + 255) / 256, 256, 0, stream>>>(er, ec, bitmap, cnt, cols, E);

    cvt_bf16<<<(N * 512 / 4 + 255) / 256, 256, 0, stream>>>(x, xb, N * 512 / 4);
    transpose_w<<<dim3(16, 8, 1), 256, 0, stream>>>(pW, pWt, 512);
    transpose_w<<<dim3(16, 8, 4), 256, 0, stream>>>(W1, Wt1, 512);
    transpose_w<<<dim3(8, 8, 12), 256, 0, stream>>>(Wk, Wtk, 256);

    for (int l = 0; l < 4; ++l) {
        int K = (l == 0) ? 512 : 256;
        const unsigned short* Wt = (l == 0) ? Wt1 : Wtk + (size_t)(l - 1) * 4 * 256 * 256;
        const float* av = (l == 0) ? a1 : ak + (size_t)(l - 1) * NHEADS * 512;
        const float* bv = (l == 0) ? b1 : bk + (size_t)(l - 1) * NHEADS * 256;
        const unsigned short* Ab = (l == 0) ? xb : bufAb;

        float* wh1    = whall + (size_t)l * WHSZ;
        float* wh2    = wh1 + NHEADS * N;
        float* colsum = wh2 + NHEADS * N;

        if (l == 0)
            gemm_mfma<1><<<dim3(20, 64), 256, 0, stream>>>(
                Ab, Wt, pWt, pb, bufProj, h_bf, av, wh1, wh2, colsum, K);
        else
            gemm_mfma<0><<<dim3(16, 64), 256, 0, stream>>>(
                Ab, Wt, nullptr, nullptr, nullptr, h_bf, av, wh1, wh2, colsum, K);

        const float* prev = (l == 0) ? bufProj : bufA;
        float* outp = (l == 3) ? (float*)d_out : bufA;
        row_attn<<<N, 256, 0, stream>>>(h_bf, wh1, wh2, colsum, cnt, cols, bv, prev, outp, bufAb, N);
    }
}

// Round 10
// 214.495 us; speedup vs baseline: 1.5057x; 1.0658x over previous
//
#include <hip/hip_runtime.h>
#include <hip/hip_bf16.h>
#include <math.h>

#define NNODES 4096
#define NHEADS 4
#define MAXDEG 128

typedef __attribute__((ext_vector_type(8))) short  bf16x8;
typedef __attribute__((ext_vector_type(4))) float  f32x4;
typedef __attribute__((ext_vector_type(4))) unsigned short us4;

__device__ __forceinline__ unsigned short f2bf(float v) {
    unsigned int x = __float_as_uint(v);
    unsigned int r = (x + 0x7fffu + ((x >> 16) & 1u)) >> 16;   // RNE
    return (unsigned short)r;
}

__device__ __forceinline__ void gload_lds16(const unsigned short* g, unsigned short* l) {
    __builtin_amdgcn_global_load_lds(
        (const __attribute__((address_space(1))) unsigned int*)(g),
        (__attribute__((address_space(3))) unsigned int*)(l), 16, 0, 0);
}

// ---------------- CSR build with bitmap dedupe ----------------
__global__ __launch_bounds__(256) void build_csr(
    const int* __restrict__ er, const int* __restrict__ ec,
    unsigned int* __restrict__ bitmap, int* __restrict__ cnt,
    int* __restrict__ cols, int E)
{
    int e = blockIdx.x * 256 + threadIdx.x;
    if (e >= E) return;
    int r = er[e], c = ec[e];
    unsigned int idx = ((unsigned int)r << 12) | (unsigned int)c;
    unsigned int bit = 1u << (idx & 31);
    unsigned int old = atomicOr(&bitmap[idx >> 5], bit);
    if (!(old & bit)) {
        int slot = atomicAdd(&cnt[r], 1);
        if (slot < MAXDEG) cols[r * MAXDEG + slot] = c;
    }
}

// ---------------- fp32 -> bf16 elementwise (vectorized) ----------------
__global__ __launch_bounds__(256) void cvt_bf16(
    const float* __restrict__ in, unsigned short* __restrict__ out, int n4)
{
    int i = blockIdx.x * 256 + threadIdx.x;
    if (i >= n4) return;
    float4 v = *(const float4*)(in + (size_t)i * 4);
    us4 o; o.x = f2bf(v.x); o.y = f2bf(v.y); o.z = f2bf(v.z); o.w = f2bf(v.w);
    *(us4*)(out + (size_t)i * 4) = o;
}

// ---------------- generic W[h][k][j] fp32 -> Wt[h*256+j][K] bf16 transpose ----------------
__global__ __launch_bounds__(256) void transpose_w(
    const float* __restrict__ W, unsigned short* __restrict__ Wt, int K)
{
    __shared__ float tile[32][33];
    int k0 = blockIdx.x * 32;
    int j0 = blockIdx.y * 32;
    int h  = blockIdx.z;
    int tj = threadIdx.x & 31;
    int tk = threadIdx.x >> 5;
#pragma unroll
    for (int it = 0; it < 4; ++it) {
        int kl = tk + it * 8;
        tile[kl][tj] = W[(size_t)h * K * 256 + (size_t)(k0 + kl) * 256 + j0 + tj];
    }
    __syncthreads();
#pragma unroll
    for (int it = 0; it < 4; ++it) {
        int jl = tk + it * 8;
        Wt[(size_t)(h * 256 + j0 + jl) * K + k0 + tj] = f2bf(tile[tj][jl]);
    }
}

// ---------------- merged K=512 transpose: z<4 -> W1 heads, z==4 -> pW ----------------
__global__ __launch_bounds__(256) void transpose_w512(
    const float* __restrict__ W1, unsigned short* __restrict__ Wt1,
    const float* __restrict__ pW, unsigned short* __restrict__ pWt)
{
    __shared__ float tile[32][33];
    int k0 = blockIdx.x * 32;
    int j0 = blockIdx.y * 32;
    int z  = blockIdx.z;
    const float* W = (z < 4) ? W1 + (size_t)z * 512 * 256 : pW;
    unsigned short* Wt = (z < 4) ? Wt1 + (size_t)z * 256 * 512 : pWt;
    int tj = threadIdx.x & 31;
    int tk = threadIdx.x >> 5;
#pragma unroll
    for (int it = 0; it < 4; ++it) {
        int kl = tk + it * 8;
        tile[kl][tj] = W[(size_t)(k0 + kl) * 256 + j0 + tj];
    }
    __syncthreads();
#pragma unroll
    for (int it = 0; it < 4; ++it) {
        int jl = tk + it * 8;
        Wt[(size_t)(j0 + jl) * 512 + k0 + tj] = f2bf(tile[tj][jl]);
    }
}

// ---------------- bf16 MFMA GEMM, 64x64 tile, BK=128 (R9 champion, unchanged) ------
template <int HASPROJ>
__global__ __launch_bounds__(256) void gemm_mfma(
    const unsigned short* __restrict__ A, const unsigned short* __restrict__ Bt,
    const unsigned short* __restrict__ pBt, const float* __restrict__ pb,
    float* __restrict__ Cproj, unsigned short* __restrict__ Cbf,
    const float* __restrict__ av, float* __restrict__ wh1, float* __restrict__ wh2,
    float* __restrict__ colsum, int K)
{
    __shared__ unsigned short As[64 * 128];   // 64 rows x 256B = 16KB
    __shared__ unsigned short Bs[64 * 128];
    int tid = threadIdx.x;
    int lane = tid & 63;
    int wave = tid >> 6;
    int wr = wave >> 1, wc = wave & 1;
    int bn = blockIdx.x, bm = blockIdx.y;
    int tileM = bm * 64;
    bool isProj = HASPROJ && (bn >= 16);
    const unsigned short* B = isProj ? pBt + (size_t)(bn - 16) * 64 * K
                                     : Bt + (size_t)bn * 64 * K;

    f32x4 acc[2][2];
#pragma unroll
    for (int m = 0; m < 2; ++m)
#pragma unroll
        for (int n = 0; n < 2; ++n) acc[m][n] = (f32x4){0.f, 0.f, 0.f, 0.f};

    int rowr  = tid >> 4;                    // 0..15
    int gslot = (tid & 15) ^ (rowr & 7);
    const unsigned short* gA = A + (size_t)(tileM + rowr) * K + gslot * 8;
    const unsigned short* gB = B + (size_t)rowr * K + gslot * 8;
    unsigned short* lA = As + tid * 8;
    unsigned short* lB = Bs + tid * 8;

    int fr = lane & 15;
    int kq = lane >> 4;
    int nsteps = K >> 7;

    int arow[2], brow[2];
#pragma unroll
    for (int m = 0; m < 2; ++m) arow[m] = wr * 32 + m * 16 + fr;
#pragma unroll
    for (int n = 0; n < 2; ++n) brow[n] = wc * 32 + n * 16 + fr;

    for (int t = 0; t < nsteps; ++t) {
#pragma unroll
        for (int r = 0; r < 4; ++r) {
            gload_lds16(gA + (size_t)r * 16 * K, lA + r * 2048);
            gload_lds16(gB + (size_t)r * 16 * K, lB + r * 2048);
        }
        gA += 128; gB += 128;
        __syncthreads();
#pragma unroll
        for (int ks = 0; ks < 4; ++ks) {
            bf16x8 af[2], bfv[2];
#pragma unroll
            for (int m = 0; m < 2; ++m) {
                int sl = ((ks * 4 + kq) ^ (arow[m] & 7)) * 8;
                af[m] = *(const bf16x8*)(As + arow[m] * 128 + sl);
            }
#pragma unroll
            for (int n = 0; n < 2; ++n) {
                int sl = ((ks * 4 + kq) ^ (brow[n] & 7)) * 8;
                bfv[n] = *(const bf16x8*)(Bs + brow[n] * 128 + sl);
            }
#pragma unroll
            for (int m = 0; m < 2; ++m)
#pragma unroll
                for (int n = 0; n < 2; ++n)
                    acc[m][n] = __builtin_amdgcn_mfma_f32_16x16x32_bf16(
                        af[m], bfv[n], acc[m][n], 0, 0, 0);
        }
        if (t + 1 < nsteps) __syncthreads();
    }

    int crow0 = tileM + wr * 32;

    if (!isProj) {
        int ccol0 = bn * 64 + wc * 32;
        int head = bn >> 2;
#pragma unroll
        for (int n = 0; n < 2; ++n) {
            float s = 0.f;
#pragma unroll
            for (int m = 0; m < 2; ++m)
#pragma unroll
                for (int q = 0; q < 4; ++q) s += acc[m][n][q];
            s += __shfl_xor(s, 16);
            s += __shfl_xor(s, 32);
            if (kq == 0)
                atomicAdd(colsum + ccol0 + n * 16 + fr, s);
        }
        float c1[2], c2[2];
#pragma unroll
        for (int n = 0; n < 2; ++n) {
            int j = (ccol0 + n * 16 + fr) & 255;
            c1[n] = av[head * 512 + j];
            c2[n] = av[head * 512 + 256 + j];
        }
#pragma unroll
        for (int m = 0; m < 2; ++m)
#pragma unroll
            for (int q = 0; q < 4; ++q) {
                float p1 = 0.f, p2 = 0.f;
#pragma unroll
                for (int n = 0; n < 2; ++n) {
                    p1 += acc[m][n][q] * c1[n];
                    p2 += acc[m][n][q] * c2[n];
                }
#pragma unroll
                for (int o = 1; o < 16; o <<= 1) {
                    p1 += __shfl_xor(p1, o);
                    p2 += __shfl_xor(p2, o);
                }
                if (fr == 0) {
                    int r = crow0 + m * 16 + kq * 4 + q;
                    atomicAdd(wh1 + head * NNODES + r, p1);
                    atomicAdd(wh2 + head * NNODES + r, p2);
                }
            }
#pragma unroll
        for (int m = 0; m < 2; ++m)
#pragma unroll
            for (int n = 0; n < 2; ++n) {
                int r0 = crow0 + m * 16 + kq * 4;
                int c  = ccol0 + n * 16 + fr;
#pragma unroll
                for (int q = 0; q < 4; ++q)
                    Cbf[(size_t)(r0 + q) * 1024 + c] = f2bf(acc[m][n][q]);
            }
    } else {
        int pcol0 = (bn - 16) * 64 + wc * 32;
#pragma unroll
        for (int m = 0; m < 2; ++m)
#pragma unroll
            for (int n = 0; n < 2; ++n) {
                int r0 = crow0 + m * 16 + kq * 4;
                int c  = pcol0 + n * 16 + fr;
                float bv = pb[c & 255];
#pragma unroll
                for (int q = 0; q < 4; ++q)
                    Cproj[(size_t)(r0 + q) * 256 + c] = acc[m][n][q] + bv;
            }
    }
}

// ---------------- per-row attention: 2 rows/block, 128 thr/row, uint4 gather ----------
// head h = (tt>>5), feature-octet f = tt&31 (8 features). Half the VMEM instructions
// of the 1-row/uint2 variant; edge weights computed pre-barrier from registers.
__global__ __launch_bounds__(256) void row_attn(
    const unsigned short* __restrict__ h_bf, const float* __restrict__ wh1,
    const float* __restrict__ wh2, const float* __restrict__ colsum,
    const int* __restrict__ cnt, const int* __restrict__ cols,
    const float* __restrict__ bias, const float* __restrict__ prev,
    float* __restrict__ outp, unsigned short* __restrict__ out_bf, int N)
{
    int t = threadIdx.x;
    int rr = t >> 7;               // which of the 2 rows
    int tt = t & 127;
    int h = tt >> 5;               // head
    int f = tt & 31;               // feature-octet
    int i = blockIdx.x * 2 + rr;
    __shared__ int   colsS[2][MAXDEG];
    __shared__ float wSt[2][4][MAXDEG];
    __shared__ float fsum[2][1024];
    int deg = cnt[i];
    if (deg > MAXDEG) deg = MAXDEG;

    if (tt < deg) {
        int c = cols[i * MAXDEG + tt];
        colsS[rr][tt] = c;
#pragma unroll
        for (int hh = 0; hh < NHEADS; ++hh) {
            float s = wh1[hh * N + i] + wh2[hh * N + c];
            s = s > 0.f ? s : 0.2f * s;
            wSt[rr][hh][tt] = expf(s) - 1.f;
        }
    }
    __syncthreads();

    float a[8] = {};
    float wsum = 0.f;
    const unsigned short* hb = h_bf + h * 256 + f * 8;
#pragma unroll 2
    for (int k = 0; k < deg; ++k) {
        float w = wSt[rr][h][k];                          // broadcast within head group
        uint4 v = *(const uint4*)(hb + (size_t)colsS[rr][k] * 1024);
        wsum += w;
        a[0] += w * __uint_as_float(v.x << 16);
        a[1] += w * __uint_as_float(v.x & 0xffff0000u);
        a[2] += w * __uint_as_float(v.y << 16);
        a[3] += w * __uint_as_float(v.y & 0xffff0000u);
        a[4] += w * __uint_as_float(v.z << 16);
        a[5] += w * __uint_as_float(v.z & 0xffff0000u);
        a[6] += w * __uint_as_float(v.w << 16);
        a[7] += w * __uint_as_float(v.w & 0xffff0000u);
    }
    float inv = 1.f / ((float)NNODES + wsum);
    float sq = 0.f;
    const float* cs = colsum + h * 256 + f * 8;
#pragma unroll
    for (int j = 0; j < 8; ++j) {
        float v = (cs[j] + a[j]) * inv;
        v = v > 0.f ? v : 0.2f * v;
        a[j] = v;
        sq += v * v;
    }
#pragma unroll
    for (int o = 1; o < 32; o <<= 1) sq += __shfl_xor(sq, o);   // 32-lane group = one head
    float rinv = 1.f / fmaxf(sqrtf(sq), 1e-12f);
    const float* bb = bias + h * 256 + f * 8;
    f32x4 lo, hi;
#pragma unroll
    for (int j = 0; j < 4; ++j) lo[j] = a[j] * rinv + bb[j];
#pragma unroll
    for (int j = 0; j < 4; ++j) hi[j] = a[4 + j] * rinv + bb[4 + j];
    *(f32x4*)(&fsum[rr][h * 256 + f * 8])     = lo;
    *(f32x4*)(&fsum[rr][h * 256 + f * 8 + 4]) = hi;
    __syncthreads();

#pragma unroll
    for (int r2 = 0; r2 < 2; ++r2) {
        int ii = blockIdx.x * 2 + r2;
        float o = (fsum[r2][t] + fsum[r2][256 + t] + fsum[r2][512 + t] + fsum[r2][768 + t]) * 0.25f
                  + prev[(size_t)ii * 256 + t];
        o = o > 0.f ? o : (expf(o) - 1.f);
        outp[(size_t)ii * 256 + t] = o;
        out_bf[(size_t)ii * 256 + t] = f2bf(o);
    }
}

extern "C" void kernel_launch(void* const* d_in, const int* in_sizes, int n_in,
                              void* d_out, int out_size, void* d_ws, size_t ws_size,
                              hipStream_t stream)
{
    const float* x  = (const float*)d_in[0];
    const int*   ei = (const int*)d_in[1];
    const float* W1 = (const float*)d_in[2];
    const float* a1 = (const float*)d_in[3];
    const float* b1 = (const float*)d_in[4];
    const float* Wk = (const float*)d_in[5];
    const float* ak = (const float*)d_in[6];
    const float* bk = (const float*)d_in[7];
    const float* pW = (const float*)d_in[8];
    const float* pb = (const float*)d_in[9];
    const int N = NNODES;
    const int E = in_sizes[1] / 2;
    const int* er = ei;
    const int* ec = ei + E;

    const size_t WHSZ = (size_t)2 * NHEADS * N + 1024;   // wh1 | wh2 | colsum per layer

    float* ws = (float*)d_ws;
    size_t off = 0;
    float* bufA    = ws + off; off += (size_t)N * 256;
    float* bufProj = ws + off; off += (size_t)N * 256;
    // --- single contiguous zero region: cnt | bitmap | whall ---
    size_t zoff = off;
    int*   cnt     = (int*)(ws + off); off += N;
    unsigned int* bitmap = (unsigned int*)(ws + off); off += (size_t)N * N / 32;
    float* whall   = ws + off; off += 4 * WHSZ;
    size_t zbytes = (off - zoff) * sizeof(float);
    // --- end zero region ---
    int*   cols    = (int*)(ws + off); off += (size_t)N * MAXDEG;
    unsigned short* h_bf  = (unsigned short*)(ws + off); off += (size_t)N * 1024 / 2;  // [node][1024]
    unsigned short* xb    = (unsigned short*)(ws + off); off += (size_t)N * 512 / 2;
    unsigned short* bufAb = (unsigned short*)(ws + off); off += (size_t)N * 256 / 2;
    unsigned short* Wt1   = (unsigned short*)(ws + off); off += (size_t)4 * 256 * 512 / 2;
    unsigned short* Wtk   = (unsigned short*)(ws + off); off += (size_t)12 * 256 * 256 / 2;
    unsigned short* pWt   = (unsigned short*)(ws + off); off += (size_t)256 * 512 / 2;

    hipMemsetAsync(ws + zoff, 0, zbytes, stream);        // cnt + bitmap + all wh/colsum
    build_csr<<<(E + 255) / 256, 256, 0, stream>>>(er, ec, bitmap, cnt, cols, E);

    cvt_bf16<<<(N * 512 / 4 + 255) / 256, 256, 0, stream>>>(x, xb, N * 512 / 4);
    transpose_w512<<<dim3(16, 8, 5), 256, 0, stream>>>(W1, Wt1, pW, pWt);
    transpose_w<<<dim3(8, 8, 12), 256, 0, stream>>>(Wk, Wtk, 256);

    for (int l = 0; l < 4; ++l) {
        int K = (l == 0) ? 512 : 256;
        const unsigned short* Wt = (l == 0) ? Wt1 : Wtk + (size_t)(l - 1) * 4 * 256 * 256;
        const float* av = (l == 0) ? a1 : ak + (size_t)(l - 1) * NHEADS * 512;
        const float* bv = (l == 0) ? b1 : bk + (size_t)(l - 1) * NHEADS * 256;
        const unsigned short* Ab = (l == 0) ? xb : bufAb;

        float* wh1    = whall + (size_t)l * WHSZ;
        float* wh2    = wh1 + NHEADS * N;
        float* colsum = wh2 + NHEADS * N;

        if (l == 0)
            gemm_mfma<1><<<dim3(20, 64), 256, 0, stream>>>(
                Ab, Wt, pWt, pb, bufProj, h_bf, av, wh1, wh2, colsum, K);
        else
            gemm_mfma<0><<<dim3(16, 64), 256, 0, stream>>>(
                Ab, Wt, nullptr, nullptr, nullptr, h_bf, av, wh1, wh2, colsum, K);

        const float* prev = (l == 0) ? bufProj : bufA;
        float* outp = (l == 3) ? (float*)d_out : bufA;
        row_attn<<<N / 2, 256, 0, stream>>>(h_bf, wh1, wh2, colsum, cnt, cols, bv, prev, outp, bufAb, N);
    }
}

// Round 11
// 188.433 us; speedup vs baseline: 1.7140x; 1.1383x over previous
//
#include <hip/hip_runtime.h>
#include <hip/hip_bf16.h>
#include <math.h>

#define NNODES 4096
#define NHEADS 4
#define MAXDEG 128

typedef __attribute__((ext_vector_type(8))) short  bf16x8;
typedef __attribute__((ext_vector_type(4))) float  f32x4;
typedef __attribute__((ext_vector_type(4))) unsigned short us4;

__device__ __forceinline__ unsigned short f2bf(float v) {
    unsigned int x = __float_as_uint(v);
    unsigned int r = (x + 0x7fffu + ((x >> 16) & 1u)) >> 16;   // RNE
    return (unsigned short)r;
}

// float -> fp8 e4m3fn (OCP), RNE. Software encode (cold path) consistent with
// gfx950's hardware OCP decode.
__device__ __forceinline__ unsigned char f2f8(float v) {
    unsigned int u = __float_as_uint(v);
    unsigned int s = (u >> 24) & 0x80u;
    u &= 0x7fffffffu;
    int e = (int)(u >> 23) - 127;
    if (e < -6) {                                   // fp8-subnormal: step 2^-9
        float q = __uint_as_float(u) * 512.f;
        int m = (int)rintf(q);
        if (m <= 0) return (unsigned char)s;
        if (m >= 8) return (unsigned char)(s | 0x08);   // rounds up to 2^-6
        return (unsigned char)(s | m);
    }
    unsigned int rr = (u + 0x7ffffu + ((u >> 20) & 1u)) >> 20;  // [exp8|man3]
    int e2 = (int)(rr >> 3) - 127;
    unsigned int m3 = rr & 7u;
    if (e2 > 8 || (e2 == 8 && m3 == 7u)) return (unsigned char)(s | 0x7e);  // clamp 448
    return (unsigned char)(s | (unsigned int)((e2 + 7) << 3) | m3);
}

__device__ __forceinline__ void gload_lds16(const unsigned short* g, unsigned short* l) {
    __builtin_amdgcn_global_load_lds(
        (const __attribute__((address_space(1))) unsigned int*)(g),
        (__attribute__((address_space(3))) unsigned int*)(l), 16, 0, 0);
}

// ---------------- CSR build with bitmap dedupe ----------------
__global__ __launch_bounds__(256) void build_csr(
    const int* __restrict__ er, const int* __restrict__ ec,
    unsigned int* __restrict__ bitmap, int* __restrict__ cnt,
    int* __restrict__ cols, int E)
{
    int e = blockIdx.x * 256 + threadIdx.x;
    if (e >= E) return;
    int r = er[e], c = ec[e];
    unsigned int idx = ((unsigned int)r << 12) | (unsigned int)c;
    unsigned int bit = 1u << (idx & 31);
    unsigned int old = atomicOr(&bitmap[idx >> 5], bit);
    if (!(old & bit)) {
        int slot = atomicAdd(&cnt[r], 1);
        if (slot < MAXDEG) cols[r * MAXDEG + slot] = c;
    }
}

// ---------------- fp32 -> bf16 elementwise (vectorized) ----------------
__global__ __launch_bounds__(256) void cvt_bf16(
    const float* __restrict__ in, unsigned short* __restrict__ out, int n4)
{
    int i = blockIdx.x * 256 + threadIdx.x;
    if (i >= n4) return;
    float4 v = *(const float4*)(in + (size_t)i * 4);
    us4 o; o.x = f2bf(v.x); o.y = f2bf(v.y); o.z = f2bf(v.z); o.w = f2bf(v.w);
    *(us4*)(out + (size_t)i * 4) = o;
}

// ---------------- generic W[h][k][j] fp32 -> Wt[h*256+j][K] bf16 transpose ----------------
__global__ __launch_bounds__(256) void transpose_w(
    const float* __restrict__ W, unsigned short* __restrict__ Wt, int K)
{
    __shared__ float tile[32][33];
    int k0 = blockIdx.x * 32;
    int j0 = blockIdx.y * 32;
    int h  = blockIdx.z;
    int tj = threadIdx.x & 31;
    int tk = threadIdx.x >> 5;
#pragma unroll
    for (int it = 0; it < 4; ++it) {
        int kl = tk + it * 8;
        tile[kl][tj] = W[(size_t)h * K * 256 + (size_t)(k0 + kl) * 256 + j0 + tj];
    }
    __syncthreads();
#pragma unroll
    for (int it = 0; it < 4; ++it) {
        int jl = tk + it * 8;
        Wt[(size_t)(h * 256 + j0 + jl) * K + k0 + tj] = f2bf(tile[tj][jl]);
    }
}

// ---------------- merged K=512 transpose: z<4 -> W1 heads, z==4 -> pW ----------------
__global__ __launch_bounds__(256) void transpose_w512(
    const float* __restrict__ W1, unsigned short* __restrict__ Wt1,
    const float* __restrict__ pW, unsigned short* __restrict__ pWt)
{
    __shared__ float tile[32][33];
    int k0 = blockIdx.x * 32;
    int j0 = blockIdx.y * 32;
    int z  = blockIdx.z;
    const float* W = (z < 4) ? W1 + (size_t)z * 512 * 256 : pW;
    unsigned short* Wt = (z < 4) ? Wt1 + (size_t)z * 256 * 512 : pWt;
    int tj = threadIdx.x & 31;
    int tk = threadIdx.x >> 5;
#pragma unroll
    for (int it = 0; it < 4; ++it) {
        int kl = tk + it * 8;
        tile[kl][tj] = W[(size_t)(k0 + kl) * 256 + j0 + tj];
    }
    __syncthreads();
#pragma unroll
    for (int it = 0; it < 4; ++it) {
        int jl = tk + it * 8;
        Wt[(size_t)(j0 + jl) * 512 + k0 + tj] = f2bf(tile[tj][jl]);
    }
}

// ---------------- bf16 MFMA GEMM, 64x64 tile, BK=128 (R9/R10 loop, fp8 C-store) ------
template <int HASPROJ>
__global__ __launch_bounds__(256) void gemm_mfma(
    const unsigned short* __restrict__ A, const unsigned short* __restrict__ Bt,
    const unsigned short* __restrict__ pBt, const float* __restrict__ pb,
    float* __restrict__ Cproj, unsigned char* __restrict__ Cf8,
    const float* __restrict__ av, float* __restrict__ wh1, float* __restrict__ wh2,
    float* __restrict__ colsum, int K)
{
    __shared__ unsigned short As[64 * 128];   // 64 rows x 256B = 16KB
    __shared__ unsigned short Bs[64 * 128];
    int tid = threadIdx.x;
    int lane = tid & 63;
    int wave = tid >> 6;
    int wr = wave >> 1, wc = wave & 1;
    int bn = blockIdx.x, bm = blockIdx.y;
    int tileM = bm * 64;
    bool isProj = HASPROJ && (bn >= 16);
    const unsigned short* B = isProj ? pBt + (size_t)(bn - 16) * 64 * K
                                     : Bt + (size_t)bn * 64 * K;

    f32x4 acc[2][2];
#pragma unroll
    for (int m = 0; m < 2; ++m)
#pragma unroll
        for (int n = 0; n < 2; ++n) acc[m][n] = (f32x4){0.f, 0.f, 0.f, 0.f};

    int rowr  = tid >> 4;                    // 0..15
    int gslot = (tid & 15) ^ (rowr & 7);
    const unsigned short* gA = A + (size_t)(tileM + rowr) * K + gslot * 8;
    const unsigned short* gB = B + (size_t)rowr * K + gslot * 8;
    unsigned short* lA = As + tid * 8;
    unsigned short* lB = Bs + tid * 8;

    int fr = lane & 15;
    int kq = lane >> 4;
    int nsteps = K >> 7;

    int arow[2], brow[2];
#pragma unroll
    for (int m = 0; m < 2; ++m) arow[m] = wr * 32 + m * 16 + fr;
#pragma unroll
    for (int n = 0; n < 2; ++n) brow[n] = wc * 32 + n * 16 + fr;

    for (int t = 0; t < nsteps; ++t) {
#pragma unroll
        for (int r = 0; r < 4; ++r) {
            gload_lds16(gA + (size_t)r * 16 * K, lA + r * 2048);
            gload_lds16(gB + (size_t)r * 16 * K, lB + r * 2048);
        }
        gA += 128; gB += 128;
        __syncthreads();
#pragma unroll
        for (int ks = 0; ks < 4; ++ks) {
            bf16x8 af[2], bfv[2];
#pragma unroll
            for (int m = 0; m < 2; ++m) {
                int sl = ((ks * 4 + kq) ^ (arow[m] & 7)) * 8;
                af[m] = *(const bf16x8*)(As + arow[m] * 128 + sl);
            }
#pragma unroll
            for (int n = 0; n < 2; ++n) {
                int sl = ((ks * 4 + kq) ^ (brow[n] & 7)) * 8;
                bfv[n] = *(const bf16x8*)(Bs + brow[n] * 128 + sl);
            }
#pragma unroll
            for (int m = 0; m < 2; ++m)
#pragma unroll
                for (int n = 0; n < 2; ++n)
                    acc[m][n] = __builtin_amdgcn_mfma_f32_16x16x32_bf16(
                        af[m], bfv[n], acc[m][n], 0, 0, 0);
        }
        if (t + 1 < nsteps) __syncthreads();
    }

    int crow0 = tileM + wr * 32;

    if (!isProj) {
        int ccol0 = bn * 64 + wc * 32;
        int head = bn >> 2;
#pragma unroll
        for (int n = 0; n < 2; ++n) {
            float s = 0.f;
#pragma unroll
            for (int m = 0; m < 2; ++m)
#pragma unroll
                for (int q = 0; q < 4; ++q) s += acc[m][n][q];
            s += __shfl_xor(s, 16);
            s += __shfl_xor(s, 32);
            if (kq == 0)
                atomicAdd(colsum + ccol0 + n * 16 + fr, s);
        }
        float c1[2], c2[2];
#pragma unroll
        for (int n = 0; n < 2; ++n) {
            int j = (ccol0 + n * 16 + fr) & 255;
            c1[n] = av[head * 512 + j];
            c2[n] = av[head * 512 + 256 + j];
        }
#pragma unroll
        for (int m = 0; m < 2; ++m)
#pragma unroll
            for (int q = 0; q < 4; ++q) {
                float p1 = 0.f, p2 = 0.f;
#pragma unroll
                for (int n = 0; n < 2; ++n) {
                    p1 += acc[m][n][q] * c1[n];
                    p2 += acc[m][n][q] * c2[n];
                }
#pragma unroll
                for (int o = 1; o < 16; o <<= 1) {
                    p1 += __shfl_xor(p1, o);
                    p2 += __shfl_xor(p2, o);
                }
                if (fr == 0) {
                    int r = crow0 + m * 16 + kq * 4 + q;
                    atomicAdd(wh1 + head * NNODES + r, p1);
                    atomicAdd(wh2 + head * NNODES + r, p2);
                }
            }
        // fp8 C store, node-major (row stride 1024 bytes)
#pragma unroll
        for (int m = 0; m < 2; ++m)
#pragma unroll
            for (int n = 0; n < 2; ++n) {
                int r0 = crow0 + m * 16 + kq * 4;
                int c  = ccol0 + n * 16 + fr;
#pragma unroll
                for (int q = 0; q < 4; ++q)
                    Cf8[(size_t)(r0 + q) * 1024 + c] = f2f8(acc[m][n][q]);
            }
    } else {
        int pcol0 = (bn - 16) * 64 + wc * 32;
#pragma unroll
        for (int m = 0; m < 2; ++m)
#pragma unroll
            for (int n = 0; n < 2; ++n) {
                int r0 = crow0 + m * 16 + kq * 4;
                int c  = pcol0 + n * 16 + fr;
                float bv = pb[c & 255];
#pragma unroll
                for (int q = 0; q < 4; ++q)
                    Cproj[(size_t)(r0 + q) * 256 + c] = acc[m][n][q] + bv;
            }
    }
}

// ---------------- per-row attention: 2 rows/block, 128 thr/row, fp8 uint2 gather ------
// head h = (tt>>5), feature-octet f = tt&31 (8 features). 8B/lane/edge (was 16B bf16);
// hardware fp8->f32 cvt with byte-select.
__global__ __launch_bounds__(256) void row_attn(
    const unsigned char* __restrict__ h_f8, const float* __restrict__ wh1,
    const float* __restrict__ wh2, const float* __restrict__ colsum,
    const int* __restrict__ cnt, const int* __restrict__ cols,
    const float* __restrict__ bias, const float* __restrict__ prev,
    float* __restrict__ outp, unsigned short* __restrict__ out_bf, int N)
{
    int t = threadIdx.x;
    int rr = t >> 7;               // which of the 2 rows
    int tt = t & 127;
    int h = tt >> 5;               // head
    int f = tt & 31;               // feature-octet
    int i = blockIdx.x * 2 + rr;
    __shared__ int   colsS[2][MAXDEG];
    __shared__ float wSt[2][4][MAXDEG];
    __shared__ float fsum[2][1024];
    int deg = cnt[i];
    if (deg > MAXDEG) deg = MAXDEG;

    if (tt < deg) {
        int c = cols[i * MAXDEG + tt];
        colsS[rr][tt] = c;
#pragma unroll
        for (int hh = 0; hh < NHEADS; ++hh) {
            float s = wh1[hh * N + i] + wh2[hh * N + c];
            s = s > 0.f ? s : 0.2f * s;
            wSt[rr][hh][tt] = expf(s) - 1.f;
        }
    }
    __syncthreads();

    float a[8] = {};
    float wsum = 0.f;
    const unsigned char* hb = h_f8 + h * 256 + f * 8;
#pragma unroll 2
    for (int k = 0; k < deg; ++k) {
        float w = wSt[rr][h][k];                          // broadcast within head group
        uint2 v = *(const uint2*)(hb + (size_t)colsS[rr][k] * 1024);
        wsum += w;
        a[0] += w * __builtin_amdgcn_cvt_f32_fp8(v.x, 0);
        a[1] += w * __builtin_amdgcn_cvt_f32_fp8(v.x, 1);
        a[2] += w * __builtin_amdgcn_cvt_f32_fp8(v.x, 2);
        a[3] += w * __builtin_amdgcn_cvt_f32_fp8(v.x, 3);
        a[4] += w * __builtin_amdgcn_cvt_f32_fp8(v.y, 0);
        a[5] += w * __builtin_amdgcn_cvt_f32_fp8(v.y, 1);
        a[6] += w * __builtin_amdgcn_cvt_f32_fp8(v.y, 2);
        a[7] += w * __builtin_amdgcn_cvt_f32_fp8(v.y, 3);
    }
    float inv = 1.f / ((float)NNODES + wsum);
    float sq = 0.f;
    const float* cs = colsum + h * 256 + f * 8;
#pragma unroll
    for (int j = 0; j < 8; ++j) {
        float v = (cs[j] + a[j]) * inv;
        v = v > 0.f ? v : 0.2f * v;
        a[j] = v;
        sq += v * v;
    }
#pragma unroll
    for (int o = 1; o < 32; o <<= 1) sq += __shfl_xor(sq, o);   // 32-lane group = one head
    float rinv = 1.f / fmaxf(sqrtf(sq), 1e-12f);
    const float* bb = bias + h * 256 + f * 8;
    f32x4 lo, hi;
#pragma unroll
    for (int j = 0; j < 4; ++j) lo[j] = a[j] * rinv + bb[j];
#pragma unroll
    for (int j = 0; j < 4; ++j) hi[j] = a[4 + j] * rinv + bb[4 + j];
    *(f32x4*)(&fsum[rr][h * 256 + f * 8])     = lo;
    *(f32x4*)(&fsum[rr][h * 256 + f * 8 + 4]) = hi;
    __syncthreads();

#pragma unroll
    for (int r2 = 0; r2 < 2; ++r2) {
        int ii = blockIdx.x * 2 + r2;
        float o = (fsum[r2][t] + fsum[r2][256 + t] + fsum[r2][512 + t] + fsum[r2][768 + t]) * 0.25f
                  + prev[(size_t)ii * 256 + t];
        o = o > 0.f ? o : (expf(o) - 1.f);
        outp[(size_t)ii * 256 + t] = o;
        out_bf[(size_t)ii * 256 + t] = f2bf(o);
    }
}

extern "C" void kernel_launch(void* const* d_in, const int* in_sizes, int n_in,
                              void* d_out, int out_size, void* d_ws, size_t ws_size,
                              hipStream_t stream)
{
    const float* x  = (const float*)d_in[0];
    const int*   ei = (const int*)d_in[1];
    const float* W1 = (const float*)d_in[2];
    const float* a1 = (const float*)d_in[3];
    const float* b1 = (const float*)d_in[4];
    const float* Wk = (const float*)d_in[5];
    const float* ak = (const float*)d_in[6];
    const float* bk = (const float*)d_in[7];
    const float* pW = (const float*)d_in[8];
    const float* pb = (const float*)d_in[9];
    const int N = NNODES;
    const int E = in_sizes[1] / 2;
    const int* er = ei;
    const int* ec = ei + E;

    const size_t WHSZ = (size_t)2 * NHEADS * N + 1024;   // wh1 | wh2 | colsum per layer

    float* ws = (float*)d_ws;
    size_t off = 0;
    float* bufA    = ws + off; off += (size_t)N * 256;
    float* bufProj = ws + off; off += (size_t)N * 256;
    // --- single contiguous zero region: cnt | bitmap | whall ---
    size_t zoff = off;
    int*   cnt     = (int*)(ws + off); off += N;
    unsigned int* bitmap = (unsigned int*)(ws + off); off += (size_t)N * N / 32;
    float* whall   = ws + off; off += 4 * WHSZ;
    size_t zbytes = (off - zoff) * sizeof(float);
    // --- end zero region ---
    int*   cols    = (int*)(ws + off); off += (size_t)N * MAXDEG;
    unsigned char* h_f8 = (unsigned char*)(ws + off); off += (size_t)N * 1024 / 4;  // [node][1024] bytes
    unsigned short* xb    = (unsigned short*)(ws + off); off += (size_t)N * 512 / 2;
    unsigned short* bufAb = (unsigned short*)(ws + off); off += (size_t)N * 256 / 2;
    unsigned short* Wt1   = (unsigned short*)(ws + off); off += (size_t)4 * 256 * 512 / 2;
    unsigned short* Wtk   = (unsigned short*)(ws + off); off += (size_t)12 * 256 * 256 / 2;
    unsigned short* pWt   = (unsigned short*)(ws + off); off += (size_t)256 * 512 / 2;

    hipMemsetAsync(ws + zoff, 0, zbytes, stream);        // cnt + bitmap + all wh/colsum
    build_csr<<<(E + 255) / 256, 256, 0, stream>>>(er, ec, bitmap, cnt, cols, E);

    cvt_bf16<<<(N * 512 / 4 + 255) / 256, 256, 0, stream>>>(x, xb, N * 512 / 4);
    transpose_w512<<<dim3(16, 8, 5), 256, 0, stream>>>(W1, Wt1, pW, pWt);
    transpose_w<<<dim3(8, 8, 12), 256, 0, stream>>>(Wk, Wtk, 256);

    for (int l = 0; l < 4; ++l) {
        int K = (l == 0) ? 512 : 256;
        const unsigned short* Wt = (l == 0) ? Wt1 : Wtk + (size_t)(l - 1) * 4 * 256 * 256;
        const float* av = (l == 0) ? a1 : ak + (size_t)(l - 1) * NHEADS * 512;
        const float* bv = (l == 0) ? b1 : bk + (size_t)(l - 1) * NHEADS * 256;
        const unsigned short* Ab = (l == 0) ? xb : bufAb;

        float* wh1    = whall + (size_t)l * WHSZ;
        float* wh2    = wh1 + NHEADS * N;
        float* colsum = wh2 + NHEADS * N;

        if (l == 0)
            gemm_mfma<1><<<dim3(20, 64), 256, 0, stream>>>(
                Ab, Wt, pWt, pb, bufProj, h_f8, av, wh1, wh2, colsum, K);
        else
            gemm_mfma<0><<<dim3(16, 64), 256, 0, stream>>>(
                Ab, Wt, nullptr, nullptr, nullptr, h_f8, av, wh1, wh2, colsum, K);

        const float* prev = (l == 0) ? bufProj : bufA;
        float* outp = (l == 3) ? (float*)d_out : bufA;
        row_attn<<<N / 2, 256, 0, stream>>>(h_f8, wh1, wh2, colsum, cnt, cols, bv, prev, outp, bufAb, N);
    }
}